// Round 3
// baseline (491.843 us; speedup 1.0000x reference)
//
#include <hip/hip_runtime.h>
#include <math.h>

// Problem constants (fixed shape)
#define B 256
#define W 512
#define F 512
#define N 512
#define GP 8             // partial blocks per sample (both x-passes)
#define WPB (W / GP)     // 64 words per partial block

// -----------------------------------------------------------------------------
// Kernel A: t partials.  grid = B*GP, 256 threads -> 8 blocks/CU = 32 waves/CU.
// Block (b,g) handles words [g*64, g*64+64).  Thread = (half, f4):
//   half = tid>>7 handles 32 words, f4 = tid&127 covers f = f4*4..+3 (float4).
// -----------------------------------------------------------------------------
__global__ __launch_bounds__(256, 8) void tpart_kernel(
    const float* __restrict__ x,
    const float* __restrict__ wvec,
    float* __restrict__ t_part)
{
    const int blk  = blockIdx.x;
    const int g    = blk & (GP - 1);
    const int b    = blk >> 3;
    const int tid  = threadIdx.x;
    const int half = tid >> 7;     // 0..1
    const int f4   = tid & 127;

    __shared__ float s_w[WPB];
    __shared__ float s_part[2][F];

    if (tid < WPB) s_w[tid] = wvec[g * WPB + tid];
    __syncthreads();

    const float* xb = x + (size_t)b * W * F + (size_t)(g * WPB + half * 32) * F;
    float4 acc = make_float4(0.f, 0.f, 0.f, 0.f);
#pragma unroll 8
    for (int i = 0; i < 32; ++i) {
        const float4 xv = *(const float4*)(xb + (size_t)i * F + f4 * 4);
        const float  ww = s_w[half * 32 + i];
        acc.x += xv.x * ww; acc.y += xv.y * ww;
        acc.z += xv.z * ww; acc.w += xv.w * ww;
    }
    *(float4*)&s_part[half][f4 * 4] = acc;
    __syncthreads();

    t_part[(size_t)blk * F + tid]       = s_part[0][tid]       + s_part[1][tid];
    t_part[(size_t)blk * F + tid + 256] = s_part[0][tid + 256] + s_part[1][tid + 256];
}

// -----------------------------------------------------------------------------
// Kernel B: reduce t partials, Q = t@Wq, r = (1/sqrt(N)) * Wk@Q.
// grid = B, 512 threads.  Weights are L2-resident (1 MB each).
// -----------------------------------------------------------------------------
__global__ __launch_bounds__(512) void qr_kernel(
    const float* __restrict__ t_part,
    const float* __restrict__ Wq,
    const float* __restrict__ Wk,
    float* __restrict__ r_out)
{
    __shared__ float s_t[F];
    __shared__ float s_q[N];
    const int b = blockIdx.x, tid = threadIdx.x;

    float t = 0.f;
#pragma unroll
    for (int g = 0; g < GP; ++g)
        t += t_part[((size_t)b * GP + g) * F + tid];
    s_t[tid] = t;
    __syncthreads();

    // Q[tid] = sum_f t[f] * Wq[f,tid]; 8 independent accumulators
    float qa[8] = {0.f, 0.f, 0.f, 0.f, 0.f, 0.f, 0.f, 0.f};
#pragma unroll 4
    for (int f = 0; f < F; f += 8) {
#pragma unroll
        for (int j = 0; j < 8; ++j)
            qa[j] += s_t[f + j] * Wq[(size_t)(f + j) * N + tid];
    }
    s_q[tid] = ((qa[0] + qa[1]) + (qa[2] + qa[3]))
             + ((qa[4] + qa[5]) + (qa[6] + qa[7]));
    __syncthreads();

    // r[tid] = scale * sum_n Q[n] * Wk[tid,n]  (per-lane float4 row reads, L2)
    const float4* wkrow = (const float4*)(Wk + (size_t)tid * N);
    float r0 = 0.f, r1 = 0.f, r2 = 0.f, r3 = 0.f;
#pragma unroll 8
    for (int n4 = 0; n4 < N / 4; ++n4) {
        const float4 kv = wkrow[n4];
        const float4 qv = *(const float4*)&s_q[n4 * 4];
        r0 += kv.x * qv.x; r1 += kv.y * qv.y;
        r2 += kv.z * qv.z; r3 += kv.w * qv.w;
    }
    r_out[(size_t)b * F + tid] =
        ((r0 + r1) + (r2 + r3)) * 0.04419417382415922f;  // 1/sqrt(512)
}

// -----------------------------------------------------------------------------
// Kernel C: partial online softmax + weighted-x accumulation.
// grid = B*GP, 256 threads (4 waves) -> up to 8 blocks/CU = 32 waves/CU.
// Block (b,g) handles words [g*64, g*64+64); wave wv takes 16 of them.
// Writes unnormalized partial (M, L, c[512]) for exact flash-merge later.
// -----------------------------------------------------------------------------
__global__ __launch_bounds__(256, 6) void attn_part_kernel(
    const float* __restrict__ x,
    const float* __restrict__ r_in,
    float* __restrict__ c_part,
    float* __restrict__ ml_part)
{
    const int blk  = blockIdx.x;
    const int g    = blk & (GP - 1);
    const int b    = blk >> 3;
    const int tid  = threadIdx.x;
    const int lane = tid & 63;
    const int wv   = tid >> 6;    // 0..3

    __shared__ float s_c[4][F];
    __shared__ float s_m[4];
    __shared__ float s_l[4];

    const float* xb = x + (size_t)b * W * F;
    const float* rb = r_in + (size_t)b * F;
    const float4 r0 = *(const float4*)(rb + lane * 4);
    const float4 r1 = *(const float4*)(rb + 256 + lane * 4);

    float m = -INFINITY, l = 0.f;
    float4 c0 = make_float4(0.f, 0.f, 0.f, 0.f);
    float4 c1 = make_float4(0.f, 0.f, 0.f, 0.f);

    const int wbase = g * WPB + wv * 16;
#pragma unroll 2
    for (int i = 0; i < 16; i += 2) {
        const float* rowA = xb + (size_t)(wbase + i) * F;
        const float* rowB = rowA + F;
        const float4 a0 = *(const float4*)(rowA + lane * 4);
        const float4 a1 = *(const float4*)(rowA + 256 + lane * 4);
        const float4 b0 = *(const float4*)(rowB + lane * 4);
        const float4 b1 = *(const float4*)(rowB + 256 + lane * 4);

        float dA = a0.x * r0.x + a0.y * r0.y + a0.z * r0.z + a0.w * r0.w
                 + a1.x * r1.x + a1.y * r1.y + a1.z * r1.z + a1.w * r1.w;
        float dB = b0.x * r0.x + b0.y * r0.y + b0.z * r0.z + b0.w * r0.w
                 + b1.x * r1.x + b1.y * r1.y + b1.z * r1.z + b1.w * r1.w;
#pragma unroll
        for (int off = 32; off >= 1; off >>= 1) {
            dA += __shfl_xor(dA, off, 64);
            dB += __shfl_xor(dB, off, 64);
        }

        float mn = fmaxf(m, dA);
        float sc = __expf(m - mn);
        float p  = __expf(dA - mn);
        l = l * sc + p;
        c0.x = c0.x * sc + p * a0.x; c0.y = c0.y * sc + p * a0.y;
        c0.z = c0.z * sc + p * a0.z; c0.w = c0.w * sc + p * a0.w;
        c1.x = c1.x * sc + p * a1.x; c1.y = c1.y * sc + p * a1.y;
        c1.z = c1.z * sc + p * a1.z; c1.w = c1.w * sc + p * a1.w;
        m = mn;

        mn = fmaxf(m, dB);
        sc = __expf(m - mn);
        p  = __expf(dB - mn);
        l = l * sc + p;
        c0.x = c0.x * sc + p * b0.x; c0.y = c0.y * sc + p * b0.y;
        c0.z = c0.z * sc + p * b0.z; c0.w = c0.w * sc + p * b0.w;
        c1.x = c1.x * sc + p * b1.x; c1.y = c1.y * sc + p * b1.y;
        c1.z = c1.z * sc + p * b1.z; c1.w = c1.w * sc + p * b1.w;
        m = mn;
    }

    *(float4*)&s_c[wv][lane * 4]       = c0;
    *(float4*)&s_c[wv][256 + lane * 4] = c1;
    if (lane == 0) { s_m[wv] = m; s_l[wv] = l; }
    __syncthreads();

    // block-level merge of 4 wave partials (uniform across threads)
    float M = fmaxf(fmaxf(s_m[0], s_m[1]), fmaxf(s_m[2], s_m[3]));
    float a0w = __expf(s_m[0] - M), a1w = __expf(s_m[1] - M);
    float a2w = __expf(s_m[2] - M), a3w = __expf(s_m[3] - M);
    float L = a0w * s_l[0] + a1w * s_l[1] + a2w * s_l[2] + a3w * s_l[3];

#pragma unroll
    for (int k = 0; k < 2; ++k) {
        const int f = tid + k * 256;
        c_part[(size_t)blk * F + f] =
            a0w * s_c[0][f] + a1w * s_c[1][f] + a2w * s_c[2][f] + a3w * s_c[3][f];
    }
    if (tid == 0) { ml_part[blk * 2] = M; ml_part[blk * 2 + 1] = L; }
}

// -----------------------------------------------------------------------------
// Kernel D: merge GP partials per sample, normalize, project through Wv.
// grid = B, 512 threads.
// -----------------------------------------------------------------------------
__global__ __launch_bounds__(512) void combine_kernel(
    const float* __restrict__ c_part,
    const float* __restrict__ ml_part,
    const float* __restrict__ Wv,
    float* __restrict__ out)
{
    __shared__ float s_cf[F];
    const int b = blockIdx.x, tid = threadIdx.x;

    float Mg[GP];
#pragma unroll
    for (int g = 0; g < GP; ++g) Mg[g] = ml_part[(b * GP + g) * 2];
    float M = -INFINITY;
#pragma unroll
    for (int g = 0; g < GP; ++g) M = fmaxf(M, Mg[g]);

    float L = 0.f;
    float alpha[GP];
#pragma unroll
    for (int g = 0; g < GP; ++g) {
        alpha[g] = __expf(Mg[g] - M);
        L += alpha[g] * ml_part[(b * GP + g) * 2 + 1];
    }
    const float invL = 1.f / L;

    float cf = 0.f;
#pragma unroll
    for (int g = 0; g < GP; ++g)
        cf += alpha[g] * c_part[((size_t)b * GP + g) * F + tid];
    s_cf[tid] = cf * invL;
    __syncthreads();

    // out[b,tid] = sum_f cf[f] * Wv[f,tid]; 8 independent accumulators
    float oa[8] = {0.f, 0.f, 0.f, 0.f, 0.f, 0.f, 0.f, 0.f};
#pragma unroll 4
    for (int f = 0; f < F; f += 8) {
#pragma unroll
        for (int j = 0; j < 8; ++j)
            oa[j] += s_cf[f + j] * Wv[(size_t)(f + j) * N + tid];
    }
    out[(size_t)b * N + tid] = ((oa[0] + oa[1]) + (oa[2] + oa[3]))
                             + ((oa[4] + oa[5]) + (oa[6] + oa[7]));
}

// -----------------------------------------------------------------------------
// Launcher.  ws layout (floats):
//   t_part : B*GP*F   = 1,048,576  (4 MB)
//   r      : B*F      =   131,072  (512 KB)
//   c_part : B*GP*F   = 1,048,576  (4 MB)
//   ml_part: B*GP*2   =     4,096  (16 KB)
// -----------------------------------------------------------------------------
extern "C" void kernel_launch(void* const* d_in, const int* in_sizes, int n_in,
                              void* d_out, int out_size, void* d_ws, size_t ws_size,
                              hipStream_t stream)
{
    const float* x    = (const float*)d_in[0];
    const float* Wk   = (const float*)d_in[1];
    const float* Wq   = (const float*)d_in[2];
    const float* Wv   = (const float*)d_in[3];
    const float* wvec = (const float*)d_in[4];
    float* out     = (float*)d_out;
    float* t_part  = (float*)d_ws;
    float* r       = t_part + (size_t)B * GP * F;
    float* c_part  = r + (size_t)B * F;
    float* ml_part = c_part + (size_t)B * GP * F;

    tpart_kernel<<<B * GP, 256, 0, stream>>>(x, wvec, t_part);
    qr_kernel<<<B, 512, 0, stream>>>(t_part, Wq, Wk, r);
    attn_part_kernel<<<B * GP, 256, 0, stream>>>(x, r, c_part, ml_part);
    combine_kernel<<<B, 512, 0, stream>>>(c_part, ml_part, Wv, out);
}